// Round 1
// baseline (156.494 us; speedup 1.0000x reference)
//
#include <hip/hip_runtime.h>

// Packed node record: path-segment sum s and jump pointer p in 8 bytes,
// so each random gather touches exactly one cache line.
struct SP { float s; int p; };

__device__ __forceinline__ SP ldSP(const SP* __restrict__ ptr) {
    float2 v = *reinterpret_cast<const float2*>(ptr);
    SP r; r.s = v.x; r.p = __float_as_int(v.y);
    return r;
}
__device__ __forceinline__ void stSP(SP* __restrict__ ptr, float s, int p) {
    float2 v; v.x = s; v.y = __int_as_float(p);
    *reinterpret_cast<float2*>(ptr) = v;
}

// Phase 1: contrib[i] = sigmoid(attrs[i]·w + b) * (levels[i] - levels[parent[i]]),
// contrib[0] = levels[0]; pack {contrib, parent} with sentinel p=N for the root.
__global__ void k_contrib(const float* __restrict__ attrs,
                          const float* __restrict__ weight,
                          const float* __restrict__ bias,
                          const float* __restrict__ levels,
                          const int*   __restrict__ parent,
                          SP* __restrict__ buf, int N) {
    float w0 = weight[0], w1 = weight[1], w2 = weight[2], w3 = weight[3];
    float w4 = weight[4], w5 = weight[5], w6 = weight[6], w7 = weight[7];
    float b = bias[0];
    int stride = gridDim.x * blockDim.x;
    for (int i = blockIdx.x * blockDim.x + threadIdx.x; i < N; i += stride) {
        const float4* a = reinterpret_cast<const float4*>(attrs + (size_t)i * 8);
        float4 a0 = a[0];
        float4 a1 = a[1];
        float x = a0.x * w0 + a0.y * w1 + a0.z * w2 + a0.w * w3
                + a1.x * w4 + a1.y * w5 + a1.z * w6 + a1.w * w7 + b;
        float sg = 1.0f / (1.0f + __expf(-x));
        int p = parent[i];
        float c = sg * (levels[i] - levels[p]);
        if (i == 0) {
            stSP(&buf[0], levels[0], N);   // root: full level, sentinel parent
        } else {
            stSP(&buf[i], c, p);
        }
    }
}

// One pointer-doubling step: s' = s + s[p], p' = p[p]  (ping-pong buffers).
__global__ void k_double(const SP* __restrict__ in, SP* __restrict__ out, int N) {
    int stride = gridDim.x * blockDim.x;
    for (int i = blockIdx.x * blockDim.x + threadIdx.x; i < N; i += stride) {
        SP v = ldSP(&in[i]);
        if (v.p < N) {
            SP w = ldSP(&in[v.p]);
            v.s += w.s;
            v.p  = w.p;
        }
        stSP(&out[i], v.s, v.p);
    }
}

// Finish any residual chain serially (correct for ANY tree depth) and emit y_nodes.
__global__ void k_finalize(const SP* __restrict__ buf, float* __restrict__ y, int N) {
    int stride = gridDim.x * blockDim.x;
    for (int i = blockIdx.x * blockDim.x + threadIdx.x; i < N; i += stride) {
        SP v = ldSP(&buf[i]);
        float acc = v.s;
        int p = v.p;
        while (p < N) {                 // ≤ ~2 hops after 5 doublings (max depth ~40)
            SP w = ldSP(&buf[p]);
            acc += w.s;
            p = w.p;
        }
        y[i] = acc;
    }
}

// out[pixel] = y[pixel_node[pixel]], int4/float4 vectorized.
__global__ void k_gather(const float* __restrict__ y,
                         const int*   __restrict__ pix,
                         float*       __restrict__ out, int M) {
    int stride = gridDim.x * blockDim.x;
    int M4 = M >> 2;
    const int4* pix4 = reinterpret_cast<const int4*>(pix);
    float4* out4 = reinterpret_cast<float4*>(out);
    for (int i = blockIdx.x * blockDim.x + threadIdx.x; i < M4; i += stride) {
        int4 p = pix4[i];
        float4 o;
        o.x = y[p.x]; o.y = y[p.y]; o.z = y[p.z]; o.w = y[p.w];
        out4[i] = o;
    }
    // tail (M not multiple of 4)
    int tid = blockIdx.x * blockDim.x + threadIdx.x;
    for (int i = (M4 << 2) + tid; i < M; i += stride) {
        out[i] = y[pix[i]];
    }
}

extern "C" void kernel_launch(void* const* d_in, const int* in_sizes, int n_in,
                              void* d_out, int out_size, void* d_ws, size_t ws_size,
                              hipStream_t stream) {
    const float* attrs  = (const float*)d_in[0];
    const float* weight = (const float*)d_in[1];
    const float* bias   = (const float*)d_in[2];
    const float* levels = (const float*)d_in[3];
    const int*   parent = (const int*)d_in[4];
    const int*   pix    = (const int*)d_in[5];
    float* out = (float*)d_out;

    const int N = in_sizes[3];     // 2,000,000 nodes
    const int M = out_size;        // H*W pixels

    SP* buf0 = (SP*)d_ws;          // 16 MB
    SP* buf1 = buf0 + N;           // 16 MB
    float* y = (float*)buf0;       // buf0 is dead after the last doubling step

    const int BLK = 256;
    const int GRID = 2048;         // grid-stride, ~8 blocks/CU headroom

    k_contrib<<<GRID, BLK, 0, stream>>>(attrs, weight, bias, levels, parent, buf0, N);
    // 5 doubling steps cover depth 32; finalize chases the (tiny) remainder.
    k_double<<<GRID, BLK, 0, stream>>>(buf0, buf1, N);
    k_double<<<GRID, BLK, 0, stream>>>(buf1, buf0, N);
    k_double<<<GRID, BLK, 0, stream>>>(buf0, buf1, N);
    k_double<<<GRID, BLK, 0, stream>>>(buf1, buf0, N);
    k_double<<<GRID, BLK, 0, stream>>>(buf0, buf1, N);
    k_finalize<<<GRID, BLK, 0, stream>>>(buf1, y, N);
    k_gather<<<GRID, BLK, 0, stream>>>(y, pix, out, M);
}

// Round 3
// 122.990 us; speedup vs baseline: 1.2724x; 1.2724x over previous
//
#include <hip/hip_runtime.h>
#include <hip/hip_fp16.h>

// Clang native vector types — required by __builtin_nontemporal_* (HIP's
// float4/int4 are classes, which the builtin rejects).
typedef float vf4 __attribute__((ext_vector_type(4)));
typedef int   vi4 __attribute__((ext_vector_type(4)));

// Packed node record: path-segment sum s and jump pointer p in 8 bytes,
// so each random gather touches exactly one cache line.
struct SP { float s; int p; };

__device__ __forceinline__ SP ldSP(const SP* __restrict__ ptr) {
    float2 v = *reinterpret_cast<const float2*>(ptr);
    SP r; r.s = v.x; r.p = __float_as_int(v.y);
    return r;
}
__device__ __forceinline__ void stSP(SP* __restrict__ ptr, float s, int p) {
    float2 v; v.x = s; v.y = __int_as_float(p);
    *reinterpret_cast<float2*>(ptr) = v;
}

// Phase 1: contrib[i] = sigmoid(attrs[i]·w + b) * (levels[i] - levels[parent[i]]),
// contrib[0] = levels[0]; pack {contrib, parent} with sentinel p=N for the root.
// attrs is 64 MB streamed once -> nontemporal so it doesn't thrash L2.
__global__ void k_contrib(const float* __restrict__ attrs,
                          const float* __restrict__ weight,
                          const float* __restrict__ bias,
                          const float* __restrict__ levels,
                          const int*   __restrict__ parent,
                          SP* __restrict__ buf, int N) {
    float w0 = weight[0], w1 = weight[1], w2 = weight[2], w3 = weight[3];
    float w4 = weight[4], w5 = weight[5], w6 = weight[6], w7 = weight[7];
    float b = bias[0];
    int stride = gridDim.x * blockDim.x;
    const vf4* a4 = reinterpret_cast<const vf4*>(attrs);
    for (int i = blockIdx.x * blockDim.x + threadIdx.x; i < N; i += stride) {
        vf4 a0 = __builtin_nontemporal_load(&a4[2 * (size_t)i]);
        vf4 a1 = __builtin_nontemporal_load(&a4[2 * (size_t)i + 1]);
        float x = a0.x * w0 + a0.y * w1 + a0.z * w2 + a0.w * w3
                + a1.x * w4 + a1.y * w5 + a1.z * w6 + a1.w * w7 + b;
        float sg = 1.0f / (1.0f + __expf(-x));
        int p = parent[i];
        float c = sg * (levels[i] - levels[p]);   // levels[p] random: cached
        if (i == 0) {
            stSP(&buf[0], levels[0], N);   // root: full level, sentinel parent
        } else {
            stSP(&buf[i], c, p);
        }
    }
}

// Fused double-doubling: s' = s + s[p] + s[p2] + s[p3], p' = 4-ancestor.
// 3 chained gathers with early exit at the root sentinel; one 32 MB stream
// replaces two full ping-pong passes.
__global__ void k_jump4(const SP* __restrict__ in, SP* __restrict__ out, int N) {
    int stride = gridDim.x * blockDim.x;
    for (int i = blockIdx.x * blockDim.x + threadIdx.x; i < N; i += stride) {
        SP v = ldSP(&in[i]);
        #pragma unroll
        for (int k = 0; k < 3; ++k) {
            if (v.p < N) {
                SP w = ldSP(&in[v.p]);
                v.s += w.s;
                v.p  = w.p;
            }
        }
        stSP(&out[i], v.s, v.p);
    }
}

// Chase the remaining chain (4-ancestor jumps) to the root sentinel and emit
// y as fp16 (4 MB -> L2-resident for the pixel gather). Correct for any depth.
__global__ void k_final(const SP* __restrict__ buf, __half* __restrict__ y, int N) {
    int stride = gridDim.x * blockDim.x;
    for (int i = blockIdx.x * blockDim.x + threadIdx.x; i < N; i += stride) {
        SP v = ldSP(&buf[i]);
        float acc = v.s;
        int p = v.p;
        while (p < N) {               // expected ~3.6 hops, hot low-index lines
            SP w = ldSP(&buf[p]);
            acc += w.s;
            p = w.p;
        }
        y[i] = __float2half(acc);
    }
}

// out[pixel] = y[pixel_node[pixel]]. y (4 MB fp16) stays in L2; pix/out are
// pure streams -> nontemporal so they don't evict it.
__global__ void k_gather(const __half* __restrict__ y,
                         const int*   __restrict__ pix,
                         float*       __restrict__ out, int M) {
    int stride = gridDim.x * blockDim.x;
    int M4 = M >> 2;
    const vi4* pix4 = reinterpret_cast<const vi4*>(pix);
    vf4* out4 = reinterpret_cast<vf4*>(out);
    for (int i = blockIdx.x * blockDim.x + threadIdx.x; i < M4; i += stride) {
        vi4 p = __builtin_nontemporal_load(&pix4[i]);
        vf4 o;
        o.x = __half2float(y[p.x]);
        o.y = __half2float(y[p.y]);
        o.z = __half2float(y[p.z]);
        o.w = __half2float(y[p.w]);
        __builtin_nontemporal_store(o, &out4[i]);
    }
    int tid = blockIdx.x * blockDim.x + threadIdx.x;
    for (int i = (M4 << 2) + tid; i < M; i += stride) {
        out[i] = __half2float(y[pix[i]]);
    }
}

extern "C" void kernel_launch(void* const* d_in, const int* in_sizes, int n_in,
                              void* d_out, int out_size, void* d_ws, size_t ws_size,
                              hipStream_t stream) {
    const float* attrs  = (const float*)d_in[0];
    const float* weight = (const float*)d_in[1];
    const float* bias   = (const float*)d_in[2];
    const float* levels = (const float*)d_in[3];
    const int*   parent = (const int*)d_in[4];
    const int*   pix    = (const int*)d_in[5];
    float* out = (float*)d_out;

    const int N = in_sizes[3];     // 2,000,000 nodes
    const int M = out_size;        // H*W pixels

    SP* buf0 = (SP*)d_ws;                    // 16 MB
    SP* buf1 = buf0 + N;                     // 16 MB
    __half* y = (__half*)(buf1 + N);         // 4 MB

    const int BLK = 256;
    const int GRID = 2048;         // grid-stride, ~8 blocks/CU

    k_contrib<<<GRID, BLK, 0, stream>>>(attrs, weight, bias, levels, parent, buf0, N);
    k_jump4 <<<GRID, BLK, 0, stream>>>(buf0, buf1, N);   // pointers -> 4-ancestors
    k_final <<<GRID, BLK, 0, stream>>>(buf1, y, N);      // chase rest, y as fp16
    k_gather<<<GRID, BLK, 0, stream>>>(y, pix, out, M);
}

// Round 4
// 104.118 us; speedup vs baseline: 1.5030x; 1.1813x over previous
//
#include <hip/hip_runtime.h>
#include <hip/hip_fp16.h>

// Clang native vector types — required by __builtin_nontemporal_* (HIP's
// float4/int4 are classes, which the builtin rejects).
typedef float vf4 __attribute__((ext_vector_type(4)));
typedef int   vi4 __attribute__((ext_vector_type(4)));

// Packed node record: path-segment sum s and jump pointer p in 8 bytes,
// so each random gather touches exactly one cache line.
struct SP { float s; int p; };

__device__ __forceinline__ SP ldSP(const SP* __restrict__ ptr) {
    float2 v = *reinterpret_cast<const float2*>(ptr);
    SP r; r.s = v.x; r.p = __float_as_int(v.y);
    return r;
}
__device__ __forceinline__ void stSP(SP* __restrict__ ptr, float s, int p) {
    float2 v; v.x = s; v.y = __int_as_float(p);
    *reinterpret_cast<float2*>(ptr) = v;
}

#define T_PREFIX 524288   // prefix size: 4 MB packed buf = one XCD's L2

// Phase 1: contrib[i] = sigmoid(attrs[i]·w + b) * (levels[i] - levels[parent[i]]),
// contrib[0] = levels[0]; pack {contrib, parent} with sentinel p=N for the root.
// attrs is 64 MB streamed once -> nontemporal so it doesn't thrash L2.
__global__ void k_contrib(const float* __restrict__ attrs,
                          const float* __restrict__ weight,
                          const float* __restrict__ bias,
                          const float* __restrict__ levels,
                          const int*   __restrict__ parent,
                          SP* __restrict__ buf, int N) {
    float w0 = weight[0], w1 = weight[1], w2 = weight[2], w3 = weight[3];
    float w4 = weight[4], w5 = weight[5], w6 = weight[6], w7 = weight[7];
    float b = bias[0];
    int stride = gridDim.x * blockDim.x;
    const vf4* a4 = reinterpret_cast<const vf4*>(attrs);
    for (int i = blockIdx.x * blockDim.x + threadIdx.x; i < N; i += stride) {
        vf4 a0 = __builtin_nontemporal_load(&a4[2 * (size_t)i]);
        vf4 a1 = __builtin_nontemporal_load(&a4[2 * (size_t)i + 1]);
        float x = a0.x * w0 + a0.y * w1 + a0.z * w2 + a0.w * w3
                + a1.x * w4 + a1.y * w5 + a1.z * w6 + a1.w * w7 + b;
        float sg = 1.0f / (1.0f + __expf(-x));
        int p = parent[i];
        float c = sg * (levels[i] - levels[p]);   // levels[p] random: cached
        if (i == 0) {
            stSP(&buf[0], levels[0], N);   // root: full level, sentinel parent (>= T)
        } else {
            stSP(&buf[i], c, p);
        }
    }
}

// Exact path sums for the prefix [0,T): serial chase to the root. All gathers
// land inside the 4 MB prefix of buf (L2-resident; hop targets concentrate
// exponentially at low indices). Correct for any depth.
__global__ void k_prefix(const SP* __restrict__ buf,
                         float* __restrict__ yPre,
                         __half* __restrict__ y16, int T) {
    int i = blockIdx.x * blockDim.x + threadIdx.x;
    if (i >= T) return;
    float acc = 0.0f;
    int p = i;
    while (p < T) {                 // root exits via sentinel p=N >= T
        SP w = ldSP(&buf[p]);
        acc += w.s;
        p = w.p;
    }
    yPre[i] = acc;
    y16[i] = __float2half(acc);
}

// Nodes [T,N): chase until the chain drops below T (parent[i] < i, index
// shrinks ~e x per hop => expected ~1.2M total mid-region gathers), then add
// the exact prefix sum. Exact for any depth.
__global__ void k_chase(const SP* __restrict__ buf,
                        const float* __restrict__ yPre,
                        __half* __restrict__ y16, int T, int N) {
    int i = T + blockIdx.x * blockDim.x + threadIdx.x;
    if (i >= N) return;
    float acc = 0.0f;
    int p = i;
    while (p >= T) {                // first iteration = coalesced self-read
        SP w = ldSP(&buf[p]);
        acc += w.s;
        p = w.p;
    }
    y16[i] = __float2half(acc + yPre[p]);
}

// out[pixel] = y[pixel_node[pixel]]. y (4 MB fp16) stays hot; pix/out are
// pure streams -> nontemporal so they don't evict it.
__global__ void k_gather(const __half* __restrict__ y,
                         const int*   __restrict__ pix,
                         float*       __restrict__ out, int M) {
    int stride = gridDim.x * blockDim.x;
    int M4 = M >> 2;
    const vi4* pix4 = reinterpret_cast<const vi4*>(pix);
    vf4* out4 = reinterpret_cast<vf4*>(out);
    for (int i = blockIdx.x * blockDim.x + threadIdx.x; i < M4; i += stride) {
        vi4 p = __builtin_nontemporal_load(&pix4[i]);
        vf4 o;
        o.x = __half2float(y[p.x]);
        o.y = __half2float(y[p.y]);
        o.z = __half2float(y[p.z]);
        o.w = __half2float(y[p.w]);
        __builtin_nontemporal_store(o, &out4[i]);
    }
    int tid = blockIdx.x * blockDim.x + threadIdx.x;
    for (int i = (M4 << 2) + tid; i < M; i += stride) {
        out[i] = __half2float(y[pix[i]]);
    }
}

extern "C" void kernel_launch(void* const* d_in, const int* in_sizes, int n_in,
                              void* d_out, int out_size, void* d_ws, size_t ws_size,
                              hipStream_t stream) {
    const float* attrs  = (const float*)d_in[0];
    const float* weight = (const float*)d_in[1];
    const float* bias   = (const float*)d_in[2];
    const float* levels = (const float*)d_in[3];
    const int*   parent = (const int*)d_in[4];
    const int*   pix    = (const int*)d_in[5];
    float* out = (float*)d_out;

    const int N = in_sizes[3];     // 2,000,000 nodes
    const int M = out_size;        // H*W pixels
    const int T = T_PREFIX;

    SP* buf      = (SP*)d_ws;                 // 16 MB packed {contrib, parent}
    __half* y16  = (__half*)(buf + N);        // 4 MB
    float* yPre  = (float*)(y16 + N);         // 2 MB (prefix exact sums, f32)

    const int BLK = 256;

    k_contrib<<<2048, BLK, 0, stream>>>(attrs, weight, bias, levels, parent, buf, N);
    k_prefix <<<(T + BLK - 1) / BLK, BLK, 0, stream>>>(buf, yPre, y16, T);
    k_chase  <<<(N - T + BLK - 1) / BLK, BLK, 0, stream>>>(buf, yPre, y16, T, N);
    k_gather <<<2048, BLK, 0, stream>>>(y16, pix, out, M);
}

// Round 5
// 102.142 us; speedup vs baseline: 1.5321x; 1.0193x over previous
//
#include <hip/hip_runtime.h>
#include <hip/hip_fp16.h>

// Clang native vector types — required by __builtin_nontemporal_* (HIP's
// float4/int4 are classes, which the builtin rejects).
typedef float vf4 __attribute__((ext_vector_type(4)));
typedef int   vi4 __attribute__((ext_vector_type(4)));

// Packed node record: path-segment sum s and jump pointer p in 8 bytes,
// so each random gather touches exactly one cache line.
struct SP { float s; int p; };

__device__ __forceinline__ SP ldSP(const SP* __restrict__ ptr) {
    float2 v = *reinterpret_cast<const float2*>(ptr);
    SP r; r.s = v.x; r.p = __float_as_int(v.y);
    return r;
}
__device__ __forceinline__ void stSP(SP* __restrict__ ptr, float s, int p) {
    float2 v; v.x = s; v.y = __int_as_float(p);
    *reinterpret_cast<float2*>(ptr) = v;
}

// Phase 1: contrib[i] = sigmoid(attrs[i]·w + b) * (levels[i] - levels[parent[i]]),
// contrib[0] = levels[0]; pack {contrib, parent} with sentinel p=N for the root.
// attrs is 64 MB streamed once -> nontemporal so it doesn't thrash L2.
__global__ void k_contrib(const float* __restrict__ attrs,
                          const float* __restrict__ weight,
                          const float* __restrict__ bias,
                          const float* __restrict__ levels,
                          const int*   __restrict__ parent,
                          SP* __restrict__ buf, int N) {
    float w0 = weight[0], w1 = weight[1], w2 = weight[2], w3 = weight[3];
    float w4 = weight[4], w5 = weight[5], w6 = weight[6], w7 = weight[7];
    float b = bias[0];
    int stride = gridDim.x * blockDim.x;
    const vf4* a4 = reinterpret_cast<const vf4*>(attrs);
    for (int i = blockIdx.x * blockDim.x + threadIdx.x; i < N; i += stride) {
        vf4 a0 = __builtin_nontemporal_load(&a4[2 * (size_t)i]);
        vf4 a1 = __builtin_nontemporal_load(&a4[2 * (size_t)i + 1]);
        float x = a0.x * w0 + a0.y * w1 + a0.z * w2 + a0.w * w3
                + a1.x * w4 + a1.y * w5 + a1.z * w6 + a1.w * w7 + b;
        float sg = 1.0f / (1.0f + __expf(-x));
        int p = parent[i];
        float c = sg * (levels[i] - levels[p]);   // levels[p] random: cached
        if (i == 0) {
            stSP(&buf[0], levels[0], N);   // root: full level, sentinel parent
        } else {
            stSP(&buf[i], c, p);
        }
    }
}

// One ladder level [lo,hi): chase the chain only while it stays >= lo
// (parent index shrinks ~e x per hop, so E[hops] ~= ln(i/lo) ~ 1), then add
// the exact, already-computed sum yAll[p] from the levels below (hot: that
// region is <= 1/4 this level's size). Bottom level (lo=0) exits at the
// root's sentinel p=N. Exact for any tree depth.
__global__ void k_level(const SP* __restrict__ buf,
                        float* __restrict__ yAll,
                        __half* __restrict__ y16,
                        int lo, int hi, int N) {
    int i = lo + blockIdx.x * blockDim.x + threadIdx.x;
    if (i >= hi) return;
    float acc = 0.0f;
    int p = i;                       // first gather = coalesced self-read
    while (p >= lo && p < N) {
        SP w = ldSP(&buf[p]);
        acc += w.s;
        p = w.p;
    }
    if (p < lo) acc += yAll[p];      // exact sum from lower levels
    yAll[i] = acc;
    y16[i] = __float2half(acc);
}

// out[pixel] = y[pixel_node[pixel]]. y16 (4 MB fp16) stays L2-hot; pix/out
// are pure streams -> nontemporal so they don't evict it.
__global__ void k_gather(const __half* __restrict__ y,
                         const int*   __restrict__ pix,
                         float*       __restrict__ out, int M) {
    int stride = gridDim.x * blockDim.x;
    int M4 = M >> 2;
    const vi4* pix4 = reinterpret_cast<const vi4*>(pix);
    vf4* out4 = reinterpret_cast<vf4*>(out);
    for (int i = blockIdx.x * blockDim.x + threadIdx.x; i < M4; i += stride) {
        vi4 p = __builtin_nontemporal_load(&pix4[i]);
        vf4 o;
        o.x = __half2float(y[p.x]);
        o.y = __half2float(y[p.y]);
        o.z = __half2float(y[p.z]);
        o.w = __half2float(y[p.w]);
        __builtin_nontemporal_store(o, &out4[i]);
    }
    int tid = blockIdx.x * blockDim.x + threadIdx.x;
    for (int i = (M4 << 2) + tid; i < M; i += stride) {
        out[i] = __half2float(y[pix[i]]);
    }
}

extern "C" void kernel_launch(void* const* d_in, const int* in_sizes, int n_in,
                              void* d_out, int out_size, void* d_ws, size_t ws_size,
                              hipStream_t stream) {
    const float* attrs  = (const float*)d_in[0];
    const float* weight = (const float*)d_in[1];
    const float* bias   = (const float*)d_in[2];
    const float* levels = (const float*)d_in[3];
    const int*   parent = (const int*)d_in[4];
    const int*   pix    = (const int*)d_in[5];
    float* out = (float*)d_out;

    const int N = in_sizes[3];     // 2,000,000 nodes
    const int M = out_size;        // H*W pixels

    SP* buf      = (SP*)d_ws;                 // 16 MB packed {contrib, parent}
    __half* y16  = (__half*)(buf + N);        // 4 MB
    float* yAll  = (float*)(y16 + N);         // 8 MB exact f32 path sums

    const int BLK = 256;

    k_contrib<<<2048, BLK, 0, stream>>>(attrs, weight, bias, levels, parent, buf, N);

    // Geometric ladder, bottom-up. Each level's random gathers stay inside
    // its own (small) region; lower levels are already exact.
    const int T0 = 0, T1 = 32768, T2 = 131072, T3 = 524288;
    k_level<<<(T1 - T0 + BLK - 1) / BLK, BLK, 0, stream>>>(buf, yAll, y16, T0, T1, N);
    k_level<<<(T2 - T1 + BLK - 1) / BLK, BLK, 0, stream>>>(buf, yAll, y16, T1, T2, N);
    k_level<<<(T3 - T2 + BLK - 1) / BLK, BLK, 0, stream>>>(buf, yAll, y16, T2, T3, N);
    k_level<<<(N  - T3 + BLK - 1) / BLK, BLK, 0, stream>>>(buf, yAll, y16, T3, N,  N);

    k_gather<<<2048, BLK, 0, stream>>>(y16, pix, out, M);
}